// Round 1
// baseline (178.232 us; speedup 1.0000x reference)
//
#include <hip/hip_runtime.h>

#define DIM 1024
#define NQ 10

// ---------- complex helpers (float2 = {re, im}) ----------
__device__ __forceinline__ float2 cmul(float2 a, float2 b) {
    return make_float2(a.x * b.x - a.y * b.y, a.x * b.y + a.y * b.x);
}
__device__ __forceinline__ float2 cadd(float2 a, float2 b) {
    return make_float2(a.x + b.x, a.y + b.y);
}
__device__ __forceinline__ float2 csub(float2 a, float2 b) {
    return make_float2(a.x - b.x, a.y - b.y);
}
__device__ __forceinline__ float2 cconj(float2 a) { return make_float2(a.x, -a.y); }

// 2x2 complex matmul, row-major arrays of 4
__device__ __forceinline__ void mm2(const float2* A, const float2* B, float2* C) {
    C[0] = cadd(cmul(A[0], B[0]), cmul(A[1], B[2]));
    C[1] = cadd(cmul(A[0], B[1]), cmul(A[1], B[3]));
    C[2] = cadd(cmul(A[2], B[0]), cmul(A[3], B[2]));
    C[3] = cadd(cmul(A[2], B[1]), cmul(A[3], B[3]));
}

// ---------- setup: per-qubit fused gates ----------
// U1[q] = Rz(+)·Ry(+)·Rx(+) (sign=+1 layer, K1)
// M[q]  = u2† Z u2 for q<6, u2 = Rz(-)·Ry(-)·Rx(-) (sign=-1 layer, K2)
__global__ void setup_gates(const float* __restrict__ weight,
                            float2* __restrict__ U1, float2* __restrict__ M) {
    int q = threadIdx.x;
    if (q >= NQ) return;
    const float WM = 0.632455532033676f;  // sqrt(2/5)
    float px = weight[q]      * WM * 0.5f;
    float py = weight[q + 10] * WM * 0.5f;
    float pz = weight[q + 20] * WM * 0.5f;
    float cx = cosf(px), sx = sinf(px);
    float cy = cosf(py), sy = sinf(py);
    float cz = cosf(pz), sz = sinf(pz);

    // sign = +1
    {
        float2 Rx[4] = { {cx, 0.f}, {0.f, -sx}, {0.f, -sx}, {cx, 0.f} };
        float2 Ry[4] = { {cy, 0.f}, {-sy, 0.f}, {sy, 0.f}, {cy, 0.f} };
        float2 Rz[4] = { {cz, -sz}, {0.f, 0.f}, {0.f, 0.f}, {cz, sz} };
        float2 T[4], u[4];
        mm2(Ry, Rx, T);
        mm2(Rz, T, u);
        U1[q * 4 + 0] = u[0]; U1[q * 4 + 1] = u[1];
        U1[q * 4 + 2] = u[2]; U1[q * 4 + 3] = u[3];
    }
    // sign = -1 (only qubits 0..5 feed the measurement operator)
    if (q < 6) {
        float nsx = -sx, nsy = -sy, nsz = -sz;
        float2 Rx[4] = { {cx, 0.f}, {0.f, -nsx}, {0.f, -nsx}, {cx, 0.f} };
        float2 Ry[4] = { {cy, 0.f}, {-nsy, 0.f}, {nsy, 0.f}, {cy, 0.f} };
        float2 Rz[4] = { {cz, -nsz}, {0.f, 0.f}, {0.f, 0.f}, {cz, nsz} };
        float2 T[4], u2[4];
        mm2(Ry, Rx, T);
        mm2(Rz, T, u2);
        // m[i][j] = conj(u2[0][i])*u2[0][j] - conj(u2[1][i])*u2[1][j]
        for (int i = 0; i < 2; i++)
            for (int j = 0; j < 2; j++) {
                float2 v = csub(cmul(cconj(u2[0 * 2 + i]), u2[0 * 2 + j]),
                                cmul(cconj(u2[1 * 2 + i]), u2[1 * 2 + j]));
                M[q * 4 + i * 2 + j] = v;
            }
    }
}

// M6[a*64+b] = prod_{q=0..5} m_q[a_q][b_q], a_q = bit (5-q) of a
__global__ void setup_m6(const float2* __restrict__ M, float2* __restrict__ M6) {
    int tid = blockIdx.x * blockDim.x + threadIdx.x;  // 0..4095
    int a = tid >> 6, b = tid & 63;
    float2 p = make_float2(1.f, 0.f);
    for (int q = 0; q < 6; q++) {
        int ia = (a >> (5 - q)) & 1;
        int ib = (b >> (5 - q)) & 1;
        p = cmul(p, M[q * 4 + ia * 2 + ib]);
    }
    M6[tid] = p;
}

// ---------- conjugation quad: B' = u B u† ----------
__device__ __forceinline__ void conj_quad(const float2* u, float2& b00, float2& b01,
                                          float2& b10, float2& b11) {
    float2 t0 = cadd(cmul(u[0], b00), cmul(u[1], b10));
    float2 t1 = cadd(cmul(u[0], b01), cmul(u[1], b11));
    float2 t2 = cadd(cmul(u[2], b00), cmul(u[3], b10));
    float2 t3 = cadd(cmul(u[2], b01), cmul(u[3], b11));
    b00 = cadd(cmul(t0, cconj(u[0])), cmul(t1, cconj(u[1])));
    b01 = cadd(cmul(t0, cconj(u[2])), cmul(t1, cconj(u[3])));
    b10 = cadd(cmul(t2, cconj(u[0])), cmul(t3, cconj(u[1])));
    b11 = cadd(cmul(t2, cconj(u[2])), cmul(t3, cconj(u[3])));
}

// first pass: qubit 0 (mask 512), reads real x, writes complex W
__global__ void conj_first(const float* __restrict__ x, const float2* __restrict__ U1,
                           float2* __restrict__ W) {
    int tid = blockIdx.x * blockDim.x + threadIdx.x;  // 0..262143
    int c = tid & 511;
    int r = tid >> 9;
    float2 u[4] = { U1[0], U1[1], U1[2], U1[3] };
    float2 b00 = make_float2(x[r * DIM + c], 0.f);
    float2 b01 = make_float2(x[r * DIM + c + 512], 0.f);
    float2 b10 = make_float2(x[(r + 512) * DIM + c], 0.f);
    float2 b11 = make_float2(x[(r + 512) * DIM + c + 512], 0.f);
    conj_quad(u, b00, b01, b10, b11);
    W[r * DIM + c] = b00;
    W[r * DIM + c + 512] = b01;
    W[(r + 512) * DIM + c] = b10;
    W[(r + 512) * DIM + c + 512] = b11;
}

// in-place pass for qubit q (1..9): W <- u_q W u_q†
__global__ void conj_pass(float2* __restrict__ W, const float2* __restrict__ U1, int q) {
    int p = 9 - q;
    int m = 1 << p;
    int lowmask = m - 1;
    int tid = blockIdx.x * blockDim.x + threadIdx.x;  // 0..262143
    int ci = tid & 511;
    int ri = tid >> 9;
    int c = ((ci & ~lowmask) << 1) | (ci & lowmask);
    int r = ((ri & ~lowmask) << 1) | (ri & lowmask);
    const float2* up = U1 + q * 4;
    float2 u[4] = { up[0], up[1], up[2], up[3] };
    float2 b00 = W[r * DIM + c];
    float2 b01 = W[r * DIM + c + m];
    float2 b10 = W[(r + m) * DIM + c];
    float2 b11 = W[(r + m) * DIM + c + m];
    conj_quad(u, b00, b01, b10, b11);
    W[r * DIM + c] = b00;
    W[r * DIM + c + m] = b01;
    W[(r + m) * DIM + c] = b10;
    W[(r + m) * DIM + c + m] = b11;
}

// out = Re( sum_{a05,b05,t} M6[a05,b05] * W[pi^-1(b05*16+t), pi^-1(a05*16+t)] )
__global__ void reduce_k(const float2* __restrict__ M6, const float2* __restrict__ W,
                         float* __restrict__ out) {
    int tid = threadIdx.x;  // 0..1023
    float acc = 0.f;
    for (int i = tid; i < 65536; i += 1024) {
        int a05 = i >> 10;
        int b05 = (i >> 4) & 63;
        int t = i & 15;
        int a = (a05 << 4) | t;
        int b = (b05 << 4) | t;
        int ra = a ^ (a >> 1);   // pi^-1(a)
        int rb = b ^ (b >> 1);   // pi^-1(b)
        float2 mm = M6[(a05 << 6) | b05];
        float2 ww = W[rb * DIM + ra];
        acc += mm.x * ww.x - mm.y * ww.y;
    }
    // wave64 reduce
    for (int off = 32; off > 0; off >>= 1)
        acc += __shfl_down(acc, off, 64);
    __shared__ float part[16];
    if ((tid & 63) == 0) part[tid >> 6] = acc;
    __syncthreads();
    if (tid == 0) {
        float s = 0.f;
        for (int w = 0; w < 16; w++) s += part[w];
        out[0] = s;
    }
}

extern "C" void kernel_launch(void* const* d_in, const int* in_sizes, int n_in,
                              void* d_out, int out_size, void* d_ws, size_t ws_size,
                              hipStream_t stream) {
    const float* x = (const float*)d_in[0];       // 1024*1024 fp32
    const float* weight = (const float*)d_in[1];  // 30 fp32
    float* out = (float*)d_out;                   // 1 fp32

    float2* ws = (float2*)d_ws;
    float2* U1 = ws;          // 40 float2 (10 gates x 4)
    float2* M  = ws + 64;     // 24 float2 (6 hermitians x 4)
    float2* M6 = ws + 128;    // 4096 float2
    float2* W  = ws + 8192;   // 1024*1024 float2 (8 MB), 64 KB offset

    setup_gates<<<1, 16, 0, stream>>>(weight, U1, M);
    setup_m6<<<16, 256, 0, stream>>>(M, M6);
    conj_first<<<512, 512, 0, stream>>>(x, U1, W);
    for (int q = 1; q < NQ; q++)
        conj_pass<<<512, 512, 0, stream>>>(W, U1, q);
    reduce_k<<<1, 1024, 0, stream>>>(M6, W, out);
}

// Round 2
// 94.295 us; speedup vs baseline: 1.8902x; 1.8902x over previous
//
#include <hip/hip_runtime.h>

#define DIM 1024
#define NQ 10

// ---------- complex helpers (float2 = {re, im}) ----------
__device__ __forceinline__ float2 cmul(float2 a, float2 b) {
    return make_float2(a.x * b.x - a.y * b.y, a.x * b.y + a.y * b.x);
}
__device__ __forceinline__ float2 cadd(float2 a, float2 b) {
    return make_float2(a.x + b.x, a.y + b.y);
}
__device__ __forceinline__ float2 csub(float2 a, float2 b) {
    return make_float2(a.x - b.x, a.y - b.y);
}
__device__ __forceinline__ float2 cconj(float2 a) { return make_float2(a.x, -a.y); }

__device__ __forceinline__ void mm2(const float2* A, const float2* B, float2* C) {
    C[0] = cadd(cmul(A[0], B[0]), cmul(A[1], B[2]));
    C[1] = cadd(cmul(A[0], B[1]), cmul(A[1], B[3]));
    C[2] = cadd(cmul(A[2], B[0]), cmul(A[3], B[2]));
    C[3] = cadd(cmul(A[2], B[1]), cmul(A[3], B[3]));
}

// ---------- setup: gates, M6 table (transposed), zero out ----------
__global__ void setup_all(const float* __restrict__ weight,
                          float2* __restrict__ U1, float2* __restrict__ M6t,
                          float* __restrict__ out) {
    __shared__ float2 Msh[24];
    int tid = threadIdx.x;
    if (tid < NQ) {
        int q = tid;
        const float WM = 0.632455532033676f;  // sqrt(2/5)
        float px = weight[q]      * WM * 0.5f;
        float py = weight[q + 10] * WM * 0.5f;
        float pz = weight[q + 20] * WM * 0.5f;
        float cx = cosf(px), sx = sinf(px);
        float cy = cosf(py), sy = sinf(py);
        float cz = cosf(pz), sz = sinf(pz);
        // sign = +1 fused gate u = Rz·Ry·Rx
        {
            float2 Rx[4] = { {cx, 0.f}, {0.f, -sx}, {0.f, -sx}, {cx, 0.f} };
            float2 Ry[4] = { {cy, 0.f}, {-sy, 0.f}, {sy, 0.f}, {cy, 0.f} };
            float2 Rz[4] = { {cz, -sz}, {0.f, 0.f}, {0.f, 0.f}, {cz, sz} };
            float2 T[4], u[4];
            mm2(Ry, Rx, T);
            mm2(Rz, T, u);
            U1[q * 4 + 0] = u[0]; U1[q * 4 + 1] = u[1];
            U1[q * 4 + 2] = u[2]; U1[q * 4 + 3] = u[3];
        }
        // sign = -1 layer: m_q = u2† Z u2 for measured qubits 0..5
        if (q < 6) {
            float nsx = -sx, nsy = -sy, nsz = -sz;
            float2 Rx[4] = { {cx, 0.f}, {0.f, -nsx}, {0.f, -nsx}, {cx, 0.f} };
            float2 Ry[4] = { {cy, 0.f}, {-nsy, 0.f}, {nsy, 0.f}, {cy, 0.f} };
            float2 Rz[4] = { {cz, -nsz}, {0.f, 0.f}, {0.f, 0.f}, {cz, nsz} };
            float2 T[4], u2[4];
            mm2(Ry, Rx, T);
            mm2(Rz, T, u2);
            for (int i = 0; i < 2; i++)
                for (int j = 0; j < 2; j++) {
                    float2 v = csub(cmul(cconj(u2[0 * 2 + i]), u2[0 * 2 + j]),
                                    cmul(cconj(u2[1 * 2 + i]), u2[1 * 2 + j]));
                    Msh[q * 4 + i * 2 + j] = v;
                }
        }
    }
    __syncthreads();
    // M6t[(b<<6)|a] = prod_q m_q[a_q][b_q]
    for (int i = tid; i < 4096; i += 256) {
        int a = i >> 6, b = i & 63;
        float2 p = make_float2(1.f, 0.f);
        for (int q = 0; q < 6; q++) {
            int ia = (a >> (5 - q)) & 1;
            int ib = (b >> (5 - q)) & 1;
            p = cmul(p, Msh[q * 4 + ia * 2 + ib]);
        }
        M6t[(b << 6) | a] = p;
    }
    if (tid == 0) out[0] = 0.f;
}

// ---------- row pass: y = K1 x, stored transposed (yt[c][r]) ----------
// Each block owns 4 consecutive columns; all 10 butterfly stages in LDS.
__global__ __launch_bounds__(512) void rowpass(const float* __restrict__ x,
                                               const float2* __restrict__ U1g,
                                               float2* __restrict__ yt) {
    __shared__ float2 L[1024 * 5];  // 4 cols + 1 pad  (40 KB)
    __shared__ float2 G[40];
    int tid = threadIdx.x;
    int c0 = blockIdx.x * 4;
    if (tid < 40) G[tid] = U1g[tid];
    for (int i = tid; i < 4096; i += 512) {
        int c = i & 3, r = i >> 2;
        L[r * 5 + c] = make_float2(x[r * DIM + c0 + c], 0.f);
    }
    __syncthreads();
    for (int q = 0; q < NQ; q++) {
        int m = 1 << (9 - q);
        float2 u0 = G[q * 4], u1 = G[q * 4 + 1], u2 = G[q * 4 + 2], u3 = G[q * 4 + 3];
        for (int k = 0; k < 4; k++) {
            int p = tid + 512 * k;
            int c = p & 3, rp = p >> 2;
            int low = rp & (m - 1);
            int r0 = ((rp ^ low) << 1) | low;
            int r1 = r0 + m;
            float2 s0 = L[r0 * 5 + c], s1 = L[r1 * 5 + c];
            L[r0 * 5 + c] = cadd(cmul(u0, s0), cmul(u1, s1));
            L[r1 * 5 + c] = cadd(cmul(u2, s0), cmul(u3, s1));
        }
        __syncthreads();
    }
    // store transposed: yt[(c0+c)*DIM + r], coalesced over r
    for (int i = tid; i < 4096; i += 512) {
        int c = i >> 10, r = i & 1023;
        yt[(c0 + c) * DIM + r] = L[r * 5 + c];
    }
}

// ---------- column pass (conj gates) + extraction + reduce ----------
// Each block owns 8 rows of y; W[R,a] = sum_c conj(K1[a,c]) y[R,c].
// out += sum_{row,a05} Re( M6[a05,b05(R)] * W[R, ra] )
__global__ __launch_bounds__(512) void colpass_reduce(const float2* __restrict__ yt,
                                                      const float2* __restrict__ U1g,
                                                      const float2* __restrict__ M6t,
                                                      float* __restrict__ out) {
    __shared__ float2 L[8 * 1025];  // 8 rows, pad +1  (~66 KB)
    __shared__ float2 G[40];
    __shared__ float part[8];
    int tid = threadIdx.x;
    int R0 = blockIdx.x * 8;
    if (tid < 40) G[tid] = U1g[tid];
    for (int i = tid; i < 8192; i += 512) {
        int row = i & 7, c = i >> 3;
        L[row * 1025 + c] = yt[c * DIM + R0 + row];
    }
    __syncthreads();
    for (int q = 0; q < NQ; q++) {
        int m = 1 << (9 - q);
        float2 u0 = cconj(G[q * 4]),     u1 = cconj(G[q * 4 + 1]);
        float2 u2 = cconj(G[q * 4 + 2]), u3 = cconj(G[q * 4 + 3]);
        for (int k = 0; k < 8; k++) {
            int p = tid + 512 * k;
            int row = p & 7, cp = p >> 3;
            int low = cp & (m - 1);
            int c0 = ((cp ^ low) << 1) | low;
            int c1 = c0 + m;
            float2 s0 = L[row * 1025 + c0], s1 = L[row * 1025 + c1];
            L[row * 1025 + c0] = cadd(cmul(u0, s0), cmul(u1, s1));
            L[row * 1025 + c1] = cadd(cmul(u2, s0), cmul(u3, s1));
        }
        __syncthreads();
    }
    // extraction: thread -> (row, a05)
    int row = tid >> 6;
    int a05 = tid & 63;
    int R = R0 + row;
    int b = R; b ^= b >> 1; b ^= b >> 2; b ^= b >> 4; b ^= b >> 8;  // prefix-xor: pi(R)
    int t = b & 15, b05 = b >> 4;
    float2 mm = M6t[(b05 << 6) | a05];
    int a = (a05 << 4) | t;
    int ra = a ^ (a >> 1);  // pi^-1(a)
    float2 wv = L[row * 1025 + ra];
    float acc = mm.x * wv.x - mm.y * wv.y;
    for (int off = 32; off > 0; off >>= 1) acc += __shfl_down(acc, off, 64);
    if ((tid & 63) == 0) part[tid >> 6] = acc;
    __syncthreads();
    if (tid == 0) {
        float s = 0.f;
        for (int w = 0; w < 8; w++) s += part[w];
        atomicAdd(out, s);
    }
}

extern "C" void kernel_launch(void* const* d_in, const int* in_sizes, int n_in,
                              void* d_out, int out_size, void* d_ws, size_t ws_size,
                              hipStream_t stream) {
    const float* x = (const float*)d_in[0];       // 1024*1024 fp32
    const float* weight = (const float*)d_in[1];  // 30 fp32
    float* out = (float*)d_out;                   // 1 fp32

    float2* ws = (float2*)d_ws;
    float2* U1  = ws;          // 40 float2
    float2* M6t = ws + 64;     // 4096 float2
    float2* yt  = ws + 8192;   // 1024*1024 float2 (8 MB)

    setup_all<<<1, 256, 0, stream>>>(weight, U1, M6t, out);
    rowpass<<<256, 512, 0, stream>>>(x, U1, yt);
    colpass_reduce<<<128, 512, 0, stream>>>(yt, U1, M6t, out);
}

// Round 3
// 93.467 us; speedup vs baseline: 1.9069x; 1.0089x over previous
//
#include <hip/hip_runtime.h>

#define DIM 1024
#define NQ 10

// ---------- complex helpers (float2 = {re, im}) ----------
__device__ __forceinline__ float2 cmul(float2 a, float2 b) {
    return make_float2(a.x * b.x - a.y * b.y, a.x * b.y + a.y * b.x);
}
__device__ __forceinline__ float2 cadd(float2 a, float2 b) {
    return make_float2(a.x + b.x, a.y + b.y);
}
__device__ __forceinline__ float2 csub(float2 a, float2 b) {
    return make_float2(a.x - b.x, a.y - b.y);
}
__device__ __forceinline__ float2 cconj(float2 a) { return make_float2(a.x, -a.y); }

__device__ __forceinline__ void mm2(const float2* A, const float2* B, float2* C) {
    C[0] = cadd(cmul(A[0], B[0]), cmul(A[1], B[2]));
    C[1] = cadd(cmul(A[0], B[1]), cmul(A[1], B[3]));
    C[2] = cadd(cmul(A[2], B[0]), cmul(A[3], B[2]));
    C[3] = cadd(cmul(A[2], B[1]), cmul(A[3], B[3]));
}

// ---------- setup: gates, M6 table, zero out ----------
// U1[q] = Rz(+w)·Ry(+w)·Rx(+w)  (K1 factor)
// M6[(a<<6)|b] = prod_{q<6} m_q[a_q][b_q], m_q = u2† Z u2 (sign=-1 gates)
__global__ void setup_all(const float* __restrict__ weight,
                          float2* __restrict__ U1, float2* __restrict__ M6,
                          float* __restrict__ out) {
    __shared__ float2 Msh[24];
    int tid = threadIdx.x;
    if (tid < NQ) {
        int q = tid;
        const float WM = 0.632455532033676f;  // sqrt(2/5)
        float px = weight[q]      * WM * 0.5f;
        float py = weight[q + 10] * WM * 0.5f;
        float pz = weight[q + 20] * WM * 0.5f;
        float cx = cosf(px), sx = sinf(px);
        float cy = cosf(py), sy = sinf(py);
        float cz = cosf(pz), sz = sinf(pz);
        {
            float2 Rx[4] = { {cx, 0.f}, {0.f, -sx}, {0.f, -sx}, {cx, 0.f} };
            float2 Ry[4] = { {cy, 0.f}, {-sy, 0.f}, {sy, 0.f}, {cy, 0.f} };
            float2 Rz[4] = { {cz, -sz}, {0.f, 0.f}, {0.f, 0.f}, {cz, sz} };
            float2 T[4], u[4];
            mm2(Ry, Rx, T);
            mm2(Rz, T, u);
            U1[q * 4 + 0] = u[0]; U1[q * 4 + 1] = u[1];
            U1[q * 4 + 2] = u[2]; U1[q * 4 + 3] = u[3];
        }
        if (q < 6) {
            float nsx = -sx, nsy = -sy, nsz = -sz;
            float2 Rx[4] = { {cx, 0.f}, {0.f, -nsx}, {0.f, -nsx}, {cx, 0.f} };
            float2 Ry[4] = { {cy, 0.f}, {-nsy, 0.f}, {nsy, 0.f}, {cy, 0.f} };
            float2 Rz[4] = { {cz, -nsz}, {0.f, 0.f}, {0.f, 0.f}, {cz, nsz} };
            float2 T[4], u2[4];
            mm2(Ry, Rx, T);
            mm2(Rz, T, u2);
            for (int i = 0; i < 2; i++)
                for (int j = 0; j < 2; j++) {
                    float2 v = csub(cmul(cconj(u2[0 * 2 + i]), u2[0 * 2 + j]),
                                    cmul(cconj(u2[1 * 2 + i]), u2[1 * 2 + j]));
                    Msh[q * 4 + i * 2 + j] = v;
                }
        }
    }
    __syncthreads();
    for (int i = tid; i < 4096; i += 256) {
        int a = i >> 6, b = i & 63;
        float2 p = make_float2(1.f, 0.f);
        for (int q = 0; q < 6; q++) {
            int ia = (a >> (5 - q)) & 1;
            int ib = (b >> (5 - q)) & 1;
            p = cmul(p, Msh[q * 4 + ia * 2 + ib]);
        }
        M6[i] = p;  // M6[(a<<6)|b]
    }
    if (tid == 0) out[0] = 0.f;
}

// ---------- all-register 1024-point gate chain ----------
// Element index e = (j<<6)|lane. Stage q pairs elements differing in
// bit (9-q): q=0..3 -> j-bit (register pairs), q=4..9 -> lane-bit (shfl_xor).
template <bool CONJ>
__device__ __forceinline__ void butterfly10(float2 v[16], const float2* __restrict__ G,
                                            int lane) {
#pragma unroll
    for (int q = 0; q < 4; q++) {
        float2 u0 = G[q * 4], u1 = G[q * 4 + 1], u2 = G[q * 4 + 2], u3 = G[q * 4 + 3];
        if (CONJ) { u0 = cconj(u0); u1 = cconj(u1); u2 = cconj(u2); u3 = cconj(u3); }
        const int h = 8 >> q;
#pragma unroll
        for (int j0 = 0; j0 < 16; j0++) {
            if ((j0 & h) == 0) {
                int j1 = j0 | h;
                float2 s0 = v[j0], s1 = v[j1];
                v[j0] = cadd(cmul(u0, s0), cmul(u1, s1));
                v[j1] = cadd(cmul(u2, s0), cmul(u3, s1));
            }
        }
    }
#pragma unroll
    for (int q = 4; q < 10; q++) {
        float2 u0 = G[q * 4], u1 = G[q * 4 + 1], u2 = G[q * 4 + 2], u3 = G[q * 4 + 3];
        if (CONJ) { u0 = cconj(u0); u1 = cconj(u1); u2 = cconj(u2); u3 = cconj(u3); }
        const int X = 1 << (9 - q);
        bool up = (lane & X) != 0;
        // branchless: new = up ? u2*partner + u3*own : u0*own + u1*partner
        float2 go = up ? u3 : u0;  // coeff on own value
        float2 gp = up ? u2 : u1;  // coeff on partner value
#pragma unroll
        for (int j = 0; j < 16; j++) {
            float2 p;
            p.x = __shfl_xor(v[j].x, X, 64);
            p.y = __shfl_xor(v[j].y, X, 64);
            v[j] = cadd(cmul(go, v[j]), cmul(gp, p));
        }
    }
}

// ---------- pass 1: z = x · K1†  (mix column index; wave per row) ----------
// coalesced loads of x row, coalesced stores of z row
__global__ __launch_bounds__(256) void pass1(const float* __restrict__ x,
                                             const float2* __restrict__ U1g,
                                             float2* __restrict__ z) {
    __shared__ float2 G[40];
    int tid = threadIdx.x;
    if (tid < 40) G[tid] = U1g[tid];
    __syncthreads();
    int lane = tid & 63;
    int r = blockIdx.x * 4 + (tid >> 6);
    float2 v[16];
#pragma unroll
    for (int j = 0; j < 16; j++)
        v[j] = make_float2(x[r * DIM + (j << 6) + lane], 0.f);
    butterfly10<true>(v, G, lane);
#pragma unroll
    for (int j = 0; j < 16; j++)
        z[r * DIM + (j << 6) + lane] = v[j];
}

// ---------- pass 2: w = K1 · z (mix row index; wave per column) + extract ----------
// out += sum over held elements (r, c): [pi(r)&15 == t(c)] * Re(M6[a05,b05] * w)
__global__ __launch_bounds__(256) void pass2(const float2* __restrict__ z,
                                             const float2* __restrict__ U1g,
                                             const float2* __restrict__ M6,
                                             float* __restrict__ out) {
    __shared__ float2 G[40];
    int tid = threadIdx.x;
    if (tid < 40) G[tid] = U1g[tid];
    __syncthreads();
    int lane = tid & 63;
    int c = blockIdx.x * 4 + (tid >> 6);
    float2 v[16];
#pragma unroll
    for (int j = 0; j < 16; j++)
        v[j] = z[((j << 6) + lane) * DIM + c];  // scattered 8B, L2/L3-resident
    butterfly10<false>(v, G, lane);

    // extraction: column c of w corresponds to a_full = pi(c)
    int af = c;
    af ^= af >> 1; af ^= af >> 2; af ^= af >> 4; af ^= af >> 8;  // pi(c), 10-bit
    int t = af & 15;
    int a05 = af >> 4;
    float2 m6v = M6[(a05 << 6) | lane];  // lane holds M6[a05, lane]
    int pl = lane;
    pl ^= pl >> 1; pl ^= pl >> 2; pl ^= pl >> 4;  // pi(lane), 6-bit
    float acc = 0.f;
#pragma unroll
    for (int j = 0; j < 16; j++) {
        // pi(r) for r = (j<<6)|lane:  high4 = pi4(j), low6 = pi(lane) ^ (parity(j)*63)
        const int p4j = j ^ (j >> 1) ^ (j >> 2) ^ (j >> 3);
        const int parmask = (p4j & 1) ? 63 : 0;
        int bf = (p4j << 6) | (pl ^ parmask);
        int b05 = bf >> 4;
        float mx = __shfl(m6v.x, b05, 64);
        float my = __shfl(m6v.y, b05, 64);
        if ((bf & 15) == t) acc += mx * v[j].x - my * v[j].y;
    }
    // wave reduce + one atomic per wave
#pragma unroll
    for (int off = 32; off > 0; off >>= 1) acc += __shfl_xor(acc, off, 64);
    if (lane == 0) atomicAdd(out, acc);
}

extern "C" void kernel_launch(void* const* d_in, const int* in_sizes, int n_in,
                              void* d_out, int out_size, void* d_ws, size_t ws_size,
                              hipStream_t stream) {
    const float* x = (const float*)d_in[0];       // 1024*1024 fp32
    const float* weight = (const float*)d_in[1];  // 30 fp32
    float* out = (float*)d_out;                   // 1 fp32

    float2* ws = (float2*)d_ws;
    float2* U1 = ws;          // 40 float2
    float2* M6 = ws + 64;     // 4096 float2
    float2* z  = ws + 8192;   // 1024*1024 float2 (8 MB), 64 KB offset

    setup_all<<<1, 256, 0, stream>>>(weight, U1, M6, out);
    pass1<<<256, 256, 0, stream>>>(x, U1, z);
    pass2<<<256, 256, 0, stream>>>(z, U1, M6, out);
}

// Round 4
// 86.430 us; speedup vs baseline: 2.0622x; 1.0814x over previous
//
#include <hip/hip_runtime.h>

#define DIM 1024
#define NQ 10

// ---------- complex helpers (float2 = {re, im}) ----------
__device__ __forceinline__ float2 cmul(float2 a, float2 b) {
    return make_float2(a.x * b.x - a.y * b.y, a.x * b.y + a.y * b.x);
}
__device__ __forceinline__ float2 cadd(float2 a, float2 b) {
    return make_float2(a.x + b.x, a.y + b.y);
}
__device__ __forceinline__ float2 csub(float2 a, float2 b) {
    return make_float2(a.x - b.x, a.y - b.y);
}
__device__ __forceinline__ float2 cconj(float2 a) { return make_float2(a.x, -a.y); }

__device__ __forceinline__ void mm2(const float2* A, const float2* B, float2* C) {
    C[0] = cadd(cmul(A[0], B[0]), cmul(A[1], B[2]));
    C[1] = cadd(cmul(A[0], B[1]), cmul(A[1], B[3]));
    C[2] = cadd(cmul(A[2], B[0]), cmul(A[3], B[2]));
    C[3] = cadd(cmul(A[2], B[1]), cmul(A[3], B[3]));
}

// ---------- per-block gate computation (replaces the setup kernel) ----------
// G[q*4..] = Rz(+w)·Ry(+w)·Rx(+w)  (K1 factor, 10 qubits)
// Msh[q*4..] = u2† Z u2 for q<6 (sign=-1 gates) if Msh != nullptr
__device__ __forceinline__ void compute_gates(const float* __restrict__ weight,
                                              float2* G, float2* Msh, int tid) {
    if (tid < NQ) {
        int q = tid;
        const float WM = 0.632455532033676f;  // sqrt(2/5)
        float px = weight[q]      * WM * 0.5f;
        float py = weight[q + 10] * WM * 0.5f;
        float pz = weight[q + 20] * WM * 0.5f;
        float cx = cosf(px), sx = sinf(px);
        float cy = cosf(py), sy = sinf(py);
        float cz = cosf(pz), sz = sinf(pz);
        {
            float2 Rx[4] = { {cx, 0.f}, {0.f, -sx}, {0.f, -sx}, {cx, 0.f} };
            float2 Ry[4] = { {cy, 0.f}, {-sy, 0.f}, {sy, 0.f}, {cy, 0.f} };
            float2 Rz[4] = { {cz, -sz}, {0.f, 0.f}, {0.f, 0.f}, {cz, sz} };
            float2 T[4], u[4];
            mm2(Ry, Rx, T);
            mm2(Rz, T, u);
            G[q * 4 + 0] = u[0]; G[q * 4 + 1] = u[1];
            G[q * 4 + 2] = u[2]; G[q * 4 + 3] = u[3];
        }
        if (Msh && q < 6) {
            float nsx = -sx, nsy = -sy, nsz = -sz;
            float2 Rx[4] = { {cx, 0.f}, {0.f, -nsx}, {0.f, -nsx}, {cx, 0.f} };
            float2 Ry[4] = { {cy, 0.f}, {-nsy, 0.f}, {nsy, 0.f}, {cy, 0.f} };
            float2 Rz[4] = { {cz, -nsz}, {0.f, 0.f}, {0.f, 0.f}, {cz, nsz} };
            float2 T[4], u2[4];
            mm2(Ry, Rx, T);
            mm2(Rz, T, u2);
            for (int i = 0; i < 2; i++)
                for (int j = 0; j < 2; j++) {
                    float2 v = csub(cmul(cconj(u2[0 * 2 + i]), u2[0 * 2 + j]),
                                    cmul(cconj(u2[1 * 2 + i]), u2[1 * 2 + j]));
                    Msh[q * 4 + i * 2 + j] = v;
                }
        }
    }
}

// ---------- pass 1: z = x · K1†  (butterfly over column index; wave per row) ----------
// Mapping: element e = (lane<<4)|j  -> stage q (pairs e-bit 9-q): q=0..5 shfl on
// lane bit 5-q; q=6..9 register pairs on j bit 9-q. Gates on distinct qubits
// commute, so stage order is free.
// Loads: 4x float4 per lane (coalesced). Stores: 8x float4 per lane.
__global__ __launch_bounds__(256) void pass1(const float* __restrict__ x,
                                             const float* __restrict__ weight,
                                             float2* __restrict__ z,
                                             float* __restrict__ out) {
    __shared__ float2 G[40];
    int tid = threadIdx.x;
    compute_gates(weight, G, nullptr, tid);
    __syncthreads();
    if (blockIdx.x == 0 && tid == 0) out[0] = 0.f;  // pass2's atomics start after pass1 retires

    int lane = tid & 63;
    int r = blockIdx.x * 4 + (tid >> 6);
    const float4* xp = (const float4*)(x + r * DIM + lane * 16);
    float2 v[16];
#pragma unroll
    for (int k = 0; k < 4; k++) {
        float4 a = xp[k];
        v[k * 4 + 0] = make_float2(a.x, 0.f);
        v[k * 4 + 1] = make_float2(a.y, 0.f);
        v[k * 4 + 2] = make_float2(a.z, 0.f);
        v[k * 4 + 3] = make_float2(a.w, 0.f);
    }
    // shfl stages: qubits 0..5 (conjugated gates: z = x·K1†)
#pragma unroll
    for (int q = 0; q < 6; q++) {
        float2 u0 = cconj(G[q * 4]),     u1 = cconj(G[q * 4 + 1]);
        float2 u2 = cconj(G[q * 4 + 2]), u3 = cconj(G[q * 4 + 3]);
        const int X = 1 << (5 - q);
        bool up = (lane & X) != 0;
        float2 go = up ? u3 : u0;
        float2 gp = up ? u2 : u1;
#pragma unroll
        for (int j = 0; j < 16; j++) {
            float2 p;
            p.x = __shfl_xor(v[j].x, X, 64);
            p.y = __shfl_xor(v[j].y, X, 64);
            v[j] = cadd(cmul(go, v[j]), cmul(gp, p));
        }
    }
    // register stages: qubits 6..9 (j bits 3..0)
#pragma unroll
    for (int q = 6; q < 10; q++) {
        float2 u0 = cconj(G[q * 4]),     u1 = cconj(G[q * 4 + 1]);
        float2 u2 = cconj(G[q * 4 + 2]), u3 = cconj(G[q * 4 + 3]);
        const int h = 1 << (9 - q);
#pragma unroll
        for (int j0 = 0; j0 < 16; j0++) {
            if ((j0 & h) == 0) {
                int j1 = j0 | h;
                float2 s0 = v[j0], s1 = v[j1];
                v[j0] = cadd(cmul(u0, s0), cmul(u1, s1));
                v[j1] = cadd(cmul(u2, s0), cmul(u3, s1));
            }
        }
    }
    float4* zp = (float4*)(z + r * DIM + lane * 16);
#pragma unroll
    for (int k = 0; k < 8; k++)
        zp[k] = make_float4(v[2 * k].x, v[2 * k].y, v[2 * k + 1].x, v[2 * k + 1].y);
}

// ---------- extraction for one column of w = K1·z ----------
// column c of w corresponds to measurement index a_full = pi(c);
// out-contribution = sum_j [pi(r)&15 == t] * Re(M6[a05, b05] * w[r,c]),
// r = (j<<6)|lane. M6 row computed inline from Msh (6-term product).
__device__ __forceinline__ float extract_col(int c, const float2 v[16], int lane,
                                             const float2* Msh) {
    int af = c;
    af ^= af >> 1; af ^= af >> 2; af ^= af >> 4; af ^= af >> 8;  // pi(c), 10-bit
    int t = af & 15;
    int a05 = af >> 4;
    float2 m6 = make_float2(1.f, 0.f);  // M6[a05, lane]
#pragma unroll
    for (int q = 0; q < 6; q++) {
        int ia = (a05 >> (5 - q)) & 1;
        int ib = (lane >> (5 - q)) & 1;
        m6 = cmul(m6, Msh[q * 4 + ia * 2 + ib]);
    }
    int pl = lane;
    pl ^= pl >> 1; pl ^= pl >> 2; pl ^= pl >> 4;  // pi(lane), 6-bit
    float acc = 0.f;
#pragma unroll
    for (int j = 0; j < 16; j++) {
        const int p4j = j ^ (j >> 1) ^ (j >> 2) ^ (j >> 3);
        const int parmask = (p4j & 1) ? 63 : 0;
        int bf = (p4j << 6) | (pl ^ parmask);  // pi(r)
        int b05 = bf >> 4;
        float mx = __shfl(m6.x, b05, 64);
        float my = __shfl(m6.y, b05, 64);
        if ((bf & 15) == t) acc += mx * v[j].x - my * v[j].y;
    }
    return acc;
}

// ---------- pass 2: w = K1·z (butterfly over row index) + extract + reduce ----------
// Wave handles 2 adjacent columns via 16-B scattered loads (halves request count).
// Mapping: row r = (j<<6)|lane -> q=0..3 register stages, q=4..9 shfl stages.
__global__ __launch_bounds__(128) void pass2(const float2* __restrict__ z,
                                             const float* __restrict__ weight,
                                             float* __restrict__ out) {
    __shared__ float2 G[40];
    __shared__ float2 Msh[24];
    int tid = threadIdx.x;
    compute_gates(weight, G, Msh, tid);
    __syncthreads();

    int lane = tid & 63;
    int c0 = blockIdx.x * 4 + (tid >> 6) * 2;  // even
    float2 v0[16], v1[16];
#pragma unroll
    for (int j = 0; j < 16; j++) {
        float4 t = *(const float4*)(z + ((j << 6) + lane) * DIM + c0);
        v0[j] = make_float2(t.x, t.y);
        v1[j] = make_float2(t.z, t.w);
    }
    // register stages: qubits 0..3 (j bits 3..0 of high nibble)
#pragma unroll
    for (int q = 0; q < 4; q++) {
        float2 u0 = G[q * 4], u1 = G[q * 4 + 1], u2 = G[q * 4 + 2], u3 = G[q * 4 + 3];
        const int h = 8 >> q;
#pragma unroll
        for (int j0 = 0; j0 < 16; j0++) {
            if ((j0 & h) == 0) {
                int j1 = j0 | h;
                {
                    float2 s0 = v0[j0], s1 = v0[j1];
                    v0[j0] = cadd(cmul(u0, s0), cmul(u1, s1));
                    v0[j1] = cadd(cmul(u2, s0), cmul(u3, s1));
                }
                {
                    float2 s0 = v1[j0], s1 = v1[j1];
                    v1[j0] = cadd(cmul(u0, s0), cmul(u1, s1));
                    v1[j1] = cadd(cmul(u2, s0), cmul(u3, s1));
                }
            }
        }
    }
    // shfl stages: qubits 4..9 (lane bits 5..0)
#pragma unroll
    for (int q = 4; q < 10; q++) {
        float2 u0 = G[q * 4], u1 = G[q * 4 + 1], u2 = G[q * 4 + 2], u3 = G[q * 4 + 3];
        const int X = 1 << (9 - q);
        bool up = (lane & X) != 0;
        float2 go = up ? u3 : u0;
        float2 gp = up ? u2 : u1;
#pragma unroll
        for (int j = 0; j < 16; j++) {
            float2 p0, p1;
            p0.x = __shfl_xor(v0[j].x, X, 64);
            p0.y = __shfl_xor(v0[j].y, X, 64);
            p1.x = __shfl_xor(v1[j].x, X, 64);
            p1.y = __shfl_xor(v1[j].y, X, 64);
            v0[j] = cadd(cmul(go, v0[j]), cmul(gp, p0));
            v1[j] = cadd(cmul(go, v1[j]), cmul(gp, p1));
        }
    }

    float acc = extract_col(c0, v0, lane, Msh) + extract_col(c0 + 1, v1, lane, Msh);
#pragma unroll
    for (int off = 32; off > 0; off >>= 1) acc += __shfl_xor(acc, off, 64);
    if (lane == 0) atomicAdd(out, acc);
}

extern "C" void kernel_launch(void* const* d_in, const int* in_sizes, int n_in,
                              void* d_out, int out_size, void* d_ws, size_t ws_size,
                              hipStream_t stream) {
    const float* x = (const float*)d_in[0];       // 1024*1024 fp32
    const float* weight = (const float*)d_in[1];  // 30 fp32
    float* out = (float*)d_out;                   // 1 fp32

    float2* z = (float2*)d_ws + 8192;  // 1024*1024 float2 (8 MB), 64 KB offset

    pass1<<<256, 256, 0, stream>>>(x, weight, z, out);
    pass2<<<256, 128, 0, stream>>>(z, weight, out);
}

// Round 5
// 81.190 us; speedup vs baseline: 2.1952x; 1.0645x over previous
//
#include <hip/hip_runtime.h>

#define DIM 1024
#define NQ 10

// ---------- complex helpers (float2 = {re, im}) ----------
__device__ __forceinline__ float2 cmul(float2 a, float2 b) {
    return make_float2(a.x * b.x - a.y * b.y, a.x * b.y + a.y * b.x);
}
__device__ __forceinline__ float2 cadd(float2 a, float2 b) {
    return make_float2(a.x + b.x, a.y + b.y);
}
__device__ __forceinline__ float2 csub(float2 a, float2 b) {
    return make_float2(a.x - b.x, a.y - b.y);
}
__device__ __forceinline__ float2 cconj(float2 a) { return make_float2(a.x, -a.y); }

__device__ __forceinline__ void mm2(const float2* A, const float2* B, float2* C) {
    C[0] = cadd(cmul(A[0], B[0]), cmul(A[1], B[2]));
    C[1] = cadd(cmul(A[0], B[1]), cmul(A[1], B[3]));
    C[2] = cadd(cmul(A[2], B[0]), cmul(A[3], B[2]));
    C[3] = cadd(cmul(A[2], B[1]), cmul(A[3], B[3]));
}

// ---------- per-block gate computation ----------
// G[q*4..] = Rz(+w)·Ry(+w)·Rx(+w)  (K1 factor, 10 qubits)
// Msh[q*4..] = u2† Z u2 for q<6 (sign=-1 gates) if Msh != nullptr
__device__ __forceinline__ void compute_gates(const float* __restrict__ weight,
                                              float2* G, float2* Msh, int tid) {
    if (tid < NQ) {
        int q = tid;
        const float WM = 0.632455532033676f;  // sqrt(2/5)
        float px = weight[q]      * WM * 0.5f;
        float py = weight[q + 10] * WM * 0.5f;
        float pz = weight[q + 20] * WM * 0.5f;
        float cx = cosf(px), sx = sinf(px);
        float cy = cosf(py), sy = sinf(py);
        float cz = cosf(pz), sz = sinf(pz);
        {
            float2 Rx[4] = { {cx, 0.f}, {0.f, -sx}, {0.f, -sx}, {cx, 0.f} };
            float2 Ry[4] = { {cy, 0.f}, {-sy, 0.f}, {sy, 0.f}, {cy, 0.f} };
            float2 Rz[4] = { {cz, -sz}, {0.f, 0.f}, {0.f, 0.f}, {cz, sz} };
            float2 T[4], u[4];
            mm2(Ry, Rx, T);
            mm2(Rz, T, u);
            G[q * 4 + 0] = u[0]; G[q * 4 + 1] = u[1];
            G[q * 4 + 2] = u[2]; G[q * 4 + 3] = u[3];
        }
        if (Msh && q < 6) {
            float nsx = -sx, nsy = -sy, nsz = -sz;
            float2 Rx[4] = { {cx, 0.f}, {0.f, -nsx}, {0.f, -nsx}, {cx, 0.f} };
            float2 Ry[4] = { {cy, 0.f}, {-nsy, 0.f}, {nsy, 0.f}, {cy, 0.f} };
            float2 Rz[4] = { {cz, -nsz}, {0.f, 0.f}, {0.f, 0.f}, {cz, nsz} };
            float2 T[4], u2[4];
            mm2(Ry, Rx, T);
            mm2(Rz, T, u2);
            for (int i = 0; i < 2; i++)
                for (int j = 0; j < 2; j++) {
                    float2 v = csub(cmul(cconj(u2[0 * 2 + i]), u2[0 * 2 + j]),
                                    cmul(cconj(u2[1 * 2 + i]), u2[1 * 2 + j]));
                    Msh[q * 4 + i * 2 + j] = v;
                }
        }
    }
}

// ---------- pass 1: z = x · K1†  (butterfly over column index; wave per row) ----------
// element e = (lane<<4)|j : q=0..5 shfl on lane bit 5-q; q=6..9 register pairs.
__global__ __launch_bounds__(256) void pass1(const float* __restrict__ x,
                                             const float* __restrict__ weight,
                                             float2* __restrict__ z,
                                             float* __restrict__ out) {
    __shared__ float2 G[40];
    int tid = threadIdx.x;
    compute_gates(weight, G, nullptr, tid);
    __syncthreads();
    if (blockIdx.x == 0 && tid == 0) out[0] = 0.f;  // pass2's atomics start after pass1 retires

    int lane = tid & 63;
    int r = blockIdx.x * 4 + (tid >> 6);
    const float4* xp = (const float4*)(x + r * DIM + lane * 16);
    float2 v[16];
#pragma unroll
    for (int k = 0; k < 4; k++) {
        float4 a = xp[k];
        v[k * 4 + 0] = make_float2(a.x, 0.f);
        v[k * 4 + 1] = make_float2(a.y, 0.f);
        v[k * 4 + 2] = make_float2(a.z, 0.f);
        v[k * 4 + 3] = make_float2(a.w, 0.f);
    }
#pragma unroll
    for (int q = 0; q < 6; q++) {
        float2 u0 = cconj(G[q * 4]),     u1 = cconj(G[q * 4 + 1]);
        float2 u2 = cconj(G[q * 4 + 2]), u3 = cconj(G[q * 4 + 3]);
        const int X = 1 << (5 - q);
        bool up = (lane & X) != 0;
        float2 go = up ? u3 : u0;
        float2 gp = up ? u2 : u1;
#pragma unroll
        for (int j = 0; j < 16; j++) {
            float2 p;
            p.x = __shfl_xor(v[j].x, X, 64);
            p.y = __shfl_xor(v[j].y, X, 64);
            v[j] = cadd(cmul(go, v[j]), cmul(gp, p));
        }
    }
#pragma unroll
    for (int q = 6; q < 10; q++) {
        float2 u0 = cconj(G[q * 4]),     u1 = cconj(G[q * 4 + 1]);
        float2 u2 = cconj(G[q * 4 + 2]), u3 = cconj(G[q * 4 + 3]);
        const int h = 1 << (9 - q);
#pragma unroll
        for (int j0 = 0; j0 < 16; j0++) {
            if ((j0 & h) == 0) {
                int j1 = j0 | h;
                float2 s0 = v[j0], s1 = v[j1];
                v[j0] = cadd(cmul(u0, s0), cmul(u1, s1));
                v[j1] = cadd(cmul(u2, s0), cmul(u3, s1));
            }
        }
    }
    float4* zp = (float4*)(z + r * DIM + lane * 16);
#pragma unroll
    for (int k = 0; k < 8; k++)
        zp[k] = make_float4(v[2 * k].x, v[2 * k].y, v[2 * k + 1].x, v[2 * k + 1].y);
}

// ---------- extraction for half the rows of one column of w = K1·z ----------
// column c corresponds to measurement index a_full = pi(c); contribution:
// sum_jj [pi(r)&15 == t] * Re(M6[a05, b05] * w[r,c]),  r = ((half*8+jj)<<6)|lane
__device__ __forceinline__ float extract_half(int c, const float2 v[8], int half,
                                              int lane, const float2* Msh) {
    int af = c;
    af ^= af >> 1; af ^= af >> 2; af ^= af >> 4; af ^= af >> 8;  // pi(c), 10-bit
    int t = af & 15;
    int a05 = af >> 4;
    float2 m6 = make_float2(1.f, 0.f);  // M6[a05, lane]
#pragma unroll
    for (int q = 0; q < 6; q++) {
        int ia = (a05 >> (5 - q)) & 1;
        int ib = (lane >> (5 - q)) & 1;
        m6 = cmul(m6, Msh[q * 4 + ia * 2 + ib]);
    }
    int pl = lane;
    pl ^= pl >> 1; pl ^= pl >> 2; pl ^= pl >> 4;  // pi(lane), 6-bit
    float acc = 0.f;
#pragma unroll
    for (int jj = 0; jj < 8; jj++) {
        int j = half * 8 + jj;
        int p4j = j ^ (j >> 1) ^ (j >> 2) ^ (j >> 3);
        int parmask = (p4j & 1) ? 63 : 0;
        int bf = (p4j << 6) | (pl ^ parmask);  // pi(r)
        int b05 = bf >> 4;
        float mx = __shfl(m6.x, b05, 64);
        float my = __shfl(m6.y, b05, 64);
        if ((bf & 15) == t) acc += mx * v[jj].x - my * v[jj].y;
    }
    return acc;
}

// ---------- pass 2: w = K1·z (butterfly over row index) + extract + reduce ----------
// 256 blocks x 256 threads (4 waves/CU). Wave pair shares 2 columns: each wave
// holds j-half (8 float2 x 2 cols). Stage q=0 (j bit 3) via one LDS exchange;
// q=1..3 register pairs (jj bits); q=4..9 shfl (lane bits). One atomic/block.
__global__ __launch_bounds__(256) void pass2(const float2* __restrict__ z,
                                             const float* __restrict__ weight,
                                             float* __restrict__ out) {
    __shared__ float2 G[40];
    __shared__ float2 Msh[24];
    __shared__ float2 ex[2 * 2 * 8 * 2 * 64];  // [pair][half][jj][col][lane], 32 KB
    __shared__ float part[4];
    int tid = threadIdx.x;
    int lane = tid & 63;
    int w = tid >> 6;       // wave 0..3
    int pair = w >> 1;      // 0,1 -> columns
    int half = w & 1;       // j-half
    int c0 = blockIdx.x * 4 + pair * 2;

    // scattered 16-B loads first (2 columns), j = half*8 + jj
    float2 v0[8], v1[8];
#pragma unroll
    for (int jj = 0; jj < 8; jj++) {
        int j = half * 8 + jj;
        float4 t = *(const float4*)(z + ((j << 6) + lane) * DIM + c0);
        v0[jj] = make_float2(t.x, t.y);
        v1[jj] = make_float2(t.z, t.w);
    }
    compute_gates(weight, G, Msh, tid);
    // write exchange buffer (lane-contiguous 8B: conflict-free)
    int sec = pair * 2 + half;
#pragma unroll
    for (int jj = 0; jj < 8; jj++) {
        ex[((sec * 8 + jj) * 2 + 0) * 64 + lane] = v0[jj];
        ex[((sec * 8 + jj) * 2 + 1) * 64 + lane] = v1[jj];
    }
    __syncthreads();
    // stage q=0: row bit 9 == j bit 3 == half (wave-uniform, no divergence)
    {
        float2 u0 = G[0], u1 = G[1], u2 = G[2], u3 = G[3];
        float2 go = half ? u3 : u0;
        float2 gp = half ? u2 : u1;
        int other = pair * 2 + (1 - half);
#pragma unroll
        for (int jj = 0; jj < 8; jj++) {
            float2 p0 = ex[((other * 8 + jj) * 2 + 0) * 64 + lane];
            float2 p1 = ex[((other * 8 + jj) * 2 + 1) * 64 + lane];
            v0[jj] = cadd(cmul(go, v0[jj]), cmul(gp, p0));
            v1[jj] = cadd(cmul(go, v1[jj]), cmul(gp, p1));
        }
    }
    // stages q=1..3: jj bits 2..0
#pragma unroll
    for (int q = 1; q < 4; q++) {
        float2 u0 = G[q * 4], u1 = G[q * 4 + 1], u2 = G[q * 4 + 2], u3 = G[q * 4 + 3];
        const int h = 8 >> q;  // 4,2,1
#pragma unroll
        for (int j0 = 0; j0 < 8; j0++) {
            if ((j0 & h) == 0) {
                int j1 = j0 | h;
                {
                    float2 s0 = v0[j0], s1 = v0[j1];
                    v0[j0] = cadd(cmul(u0, s0), cmul(u1, s1));
                    v0[j1] = cadd(cmul(u2, s0), cmul(u3, s1));
                }
                {
                    float2 s0 = v1[j0], s1 = v1[j1];
                    v1[j0] = cadd(cmul(u0, s0), cmul(u1, s1));
                    v1[j1] = cadd(cmul(u2, s0), cmul(u3, s1));
                }
            }
        }
    }
    // shfl stages q=4..9: lane bits 5..0
#pragma unroll
    for (int q = 4; q < 10; q++) {
        float2 u0 = G[q * 4], u1 = G[q * 4 + 1], u2 = G[q * 4 + 2], u3 = G[q * 4 + 3];
        const int X = 1 << (9 - q);
        bool up = (lane & X) != 0;
        float2 go = up ? u3 : u0;
        float2 gp = up ? u2 : u1;
#pragma unroll
        for (int jj = 0; jj < 8; jj++) {
            float2 p0, p1;
            p0.x = __shfl_xor(v0[jj].x, X, 64);
            p0.y = __shfl_xor(v0[jj].y, X, 64);
            p1.x = __shfl_xor(v1[jj].x, X, 64);
            p1.y = __shfl_xor(v1[jj].y, X, 64);
            v0[jj] = cadd(cmul(go, v0[jj]), cmul(gp, p0));
            v1[jj] = cadd(cmul(go, v1[jj]), cmul(gp, p1));
        }
    }

    float acc = extract_half(c0, v0, half, lane, Msh) +
                extract_half(c0 + 1, v1, half, lane, Msh);
#pragma unroll
    for (int off = 32; off > 0; off >>= 1) acc += __shfl_xor(acc, off, 64);
    if (lane == 0) part[w] = acc;
    __syncthreads();
    if (tid == 0) atomicAdd(out, part[0] + part[1] + part[2] + part[3]);
}

extern "C" void kernel_launch(void* const* d_in, const int* in_sizes, int n_in,
                              void* d_out, int out_size, void* d_ws, size_t ws_size,
                              hipStream_t stream) {
    const float* x = (const float*)d_in[0];       // 1024*1024 fp32
    const float* weight = (const float*)d_in[1];  // 30 fp32
    float* out = (float*)d_out;                   // 1 fp32

    float2* z = (float2*)d_ws + 8192;  // 1024*1024 float2 (8 MB), 64 KB offset

    pass1<<<256, 256, 0, stream>>>(x, weight, z, out);
    pass2<<<256, 256, 0, stream>>>(z, weight, out);
}